// Round 5
// baseline (154.108 us; speedup 1.0000x reference)
//
#include <hip/hip_runtime.h>

typedef unsigned short u16;
typedef unsigned int u32;
typedef __attribute__((ext_vector_type(8))) short short8;
typedef __attribute__((ext_vector_type(4))) float f32x4;
typedef __attribute__((ext_vector_type(4))) u32 u32x4;

#define BKT_SHIFT 6
#define BKT_NODES 64           // nodes per bucket == MLP tile
#define CAP 1536               // slots/bucket (mean 1024, +16 sigma)
#define EPB 4096               // edges per bin block
#define NBH 1024               // bin histogram size (pow2 >= nbuck=782)

__device__ inline u16 f2bf(float f){ u32 u=__float_as_uint(f); u32 r=((u>>16)&1u)+0x7fffu; return (u16)((u+r)>>16); }

// ---------- fused: h->bf16 cast (to ws) + weight transpose + edge binning ----------
__global__ __launch_bounds__(256) void k_castbin(
    const int* __restrict__ src, const int* __restrict__ dst,
    int* __restrict__ gcnt, u32* __restrict__ recs_g, int nE, int gB,
    const float* __restrict__ h, u16* __restrict__ hbf, int nh8,
    const float* __restrict__ w1, const float* __restrict__ w2,
    u16* __restrict__ w1t, u16* __restrict__ w2t){
  __shared__ u32 rl[EPB];
  __shared__ int hist[NBH];
  __shared__ int curs[NBH];
  int t = threadIdx.x;
  if ((int)blockIdx.x < gB){
    int e0 = blockIdx.x*EPB;
    for (int i=t;i<NBH;i+=256) hist[i]=0;
    __syncthreads();
    #pragma unroll
    for (int i=0;i<EPB/256;i++){
      int e = e0 + i*256 + t;
      u32 rec = 0xffffffffu;               // sentinel: bucket=1023, impossible
      if (e < nE){
        u32 d = (u32)dst[e];
        u32 s = (u32)src[e];
        u32 bb = d >> BKT_SHIFT;
        rec = (bb<<22) | ((d & (u32)(BKT_NODES-1))<<16) | s;
        atomicAdd(&hist[bb & (NBH-1)], 1);
      }
      rl[i*256+t] = rec;
    }
    __syncthreads();
    for (int i=t;i<NBH;i+=256){
      int c = hist[i];
      curs[i] = c ? atomicAdd(&gcnt[i], c) : 0;
    }
    __syncthreads();
    #pragma unroll
    for (int i=0;i<EPB/256;i++){
      u32 rec = rl[i*256+t];
      if (rec != 0xffffffffu){
        u32 bb = rec>>22;
        int slot = atomicAdd(&curs[bb], 1);
        if (slot < CAP) recs_g[(size_t)bb*CAP + slot] = rec & 0x3fffffu;
      }
    }
  } else {
    int e = ((int)blockIdx.x - gB)*256 + t;
    if (e < nh8){
      float4 a = *(const float4*)(h + (size_t)e*8);
      float4 b = *(const float4*)(h + (size_t)e*8 + 4);
      u32x4 p;
      p.x = (u32)f2bf(a.x) | ((u32)f2bf(a.y)<<16);
      p.y = (u32)f2bf(a.z) | ((u32)f2bf(a.w)<<16);
      p.z = (u32)f2bf(b.x) | ((u32)f2bf(b.y)<<16);
      p.w = (u32)f2bf(b.z) | ((u32)f2bf(b.w)<<16);
      *(u32x4*)(hbf + (size_t)e*8) = p;
    }
    if (e < 256*128){ int k=e>>7, nn=e&127; w1t[nn*256+k]=f2bf(w1[e]); }
    else { int j=e-256*128; if (j<128*128){ int k=j>>7, nn=j&127; w2t[nn*128+k]=f2bf(w2[j]); } }
  }
}

// ---------- per-bucket counting sort -> global sorted src lists + per-node {start,deg} ----------
__global__ __launch_bounds__(256) void k_sortscat(
    const u32* __restrict__ recs_g, const int* __restrict__ gcnt,
    u16* __restrict__ srt_g, u32* __restrict__ nd_g, int n){
  __shared__ u32 stage[CAP];
  __shared__ __align__(4) u16 srt[CAP];
  __shared__ int hist[BKT_NODES];
  __shared__ int scn[BKT_NODES];
  __shared__ int cur[BKT_NODES];
  int b = blockIdx.x, t = threadIdx.x;
  int cnt = gcnt[b]; if (cnt > CAP) cnt = CAP;
  const u32* rp = recs_g + (size_t)b*CAP;
  if (t < BKT_NODES) hist[t] = 0;
  __syncthreads();
  for (int i=t; i<cnt; i+=256){
    u32 r = rp[i];
    stage[i] = r;
    atomicAdd(&hist[(r>>16)&(BKT_NODES-1)], 1);
  }
  __syncthreads();
  if (t < BKT_NODES){                        // wave 0: shfl inclusive scan
    int v = hist[t];
    int s = v;
    #pragma unroll
    for (int d=1; d<64; d<<=1){
      int o = __shfl_up(s, d, 64);
      if (t >= d) s += o;
    }
    scn[t] = s;
    cur[t] = s - v;
  }
  __syncthreads();
  for (int i=t; i<cnt; i+=256){
    u32 r = stage[i];
    int slot = atomicAdd(&cur[(r>>16)&(BKT_NODES-1)], 1);
    srt[slot] = (u16)(r & 0xffffu);
  }
  __syncthreads();
  // vectorized copy LDS->global (full CAP: 3KB)
  const u32* sw = (const u32*)srt;
  u32* gw = (u32*)(srt_g + (size_t)b*CAP);
  for (int i=t; i<CAP/2; i+=256) gw[i] = sw[i];
  if (t < BKT_NODES){
    int node = b*BKT_NODES + t;
    if (node < n) nd_g[node] = (u32)(scn[t]-hist[t]) | ((u32)hist[t]<<16);
  }
}

// ---------- mean aggregation: wave per node, 16 full-row loads in flight ----------
// lane owns one u32 (2 bf16 cols); 64 lanes x 4B = one full 256B row per wave-load.
// Deep grid (12500 blocks) -> latency hidden by TLP+ILP, no compiler pipelining needed.
__global__ __launch_bounds__(256) void k_agg(
    const u32* __restrict__ hbfw, const u16* __restrict__ srt_g,
    const u32* __restrict__ nd_g, u32* __restrict__ outw, int n){
  int node = (int)((blockIdx.x*256 + threadIdx.x) >> 6);
  int lane = threadIdx.x & 63;
  if (node >= n) return;
  u32 nd = nd_g[node];
  int st  = (int)(nd & 0xffffu);
  int deg = (int)(nd >> 16);
  const u16* sp = srt_g + (size_t)(node>>6)*CAP + st;
  float a0=0.f, a1=0.f;
  for (int base=0; base<deg; base+=16){
    int sidx[16];
    #pragma unroll
    for (int j=0;j<16;j++){
      int jj = base + j; if (jj > deg-1) jj = deg-1;
      sidx[j] = sp[jj];
    }
    u32 vv[16];
    #pragma unroll
    for (int j=0;j<16;j++) vv[j] = hbfw[(size_t)sidx[j]*64 + lane];
    #pragma unroll
    for (int j=0;j<16;j++){
      float m = (base+j < deg) ? 1.f : 0.f;
      union{u32 u; float f;} lo,hi; lo.u=vv[j]<<16; hi.u=vv[j]&0xffff0000u;
      a0 += m*lo.f; a1 += m*hi.f;
    }
  }
  float inv = 1.f/(float)(deg>0?deg:1);
  outw[(size_t)node*128 + 64 + lane] = (u32)f2bf(a0*inv) | ((u32)f2bf(a1*inv)<<16);
}

// ---------- dense MLP: 8 waves, wave owns 16 output cols ----------
__global__ __launch_bounds__(512) void k_mlp(
    const u16* __restrict__ hbf, const u32* __restrict__ outw_in,
    const u16* __restrict__ w1t, const u16* __restrict__ w2t,
    const float* __restrict__ b1, const float* __restrict__ b2,
    float* __restrict__ out, int n){
  __shared__ __align__(16) u16 xs[64*264];
  int t = threadIdx.x;
  int node0 = blockIdx.x*64;
  int wave=t>>6, lane=t&63, quad=lane>>4, l16=lane&15;

  const u16* w1p = w1t + (size_t)(wave*16 + l16)*256 + quad*8;
  short8 wb1[8];
  #pragma unroll
  for (int ks=0;ks<8;ks++) wb1[ks] = *(const short8*)(w1p + ks*32);

  // stage: 64 rows x 32 chunks; c8<16 from hbf (h half), else agg stash in out rows
  #pragma unroll
  for (int i=0;i<4;i++){
    int idx = i*512 + t;
    int row = idx>>5, c8 = idx&31;
    int node = node0 + row;
    u32x4 v = {0,0,0,0};
    if (node < n){
      if (c8 < 16) v = *(const u32x4*)(hbf + (size_t)node*128 + c8*8);
      else         v = *(const u32x4*)(outw_in + (size_t)node*128 + 64 + (c8-16)*4);
    }
    *(u32x4*)(&xs[row*264 + c8*8]) = v;
  }
  __syncthreads();

  f32x4 acc[4];
  #pragma unroll
  for (int m=0;m<4;m++) acc[m]=(f32x4){0,0,0,0};
  #pragma unroll
  for (int ks=0;ks<8;ks++){
    #pragma unroll
    for (int m=0;m<4;m++){
      short8 av = *(const short8*)(&xs[(m*16+l16)*264 + ks*32 + quad*8]);
      acc[m] = __builtin_amdgcn_mfma_f32_16x16x32_bf16(av, wb1[ks], acc[m],0,0,0);
    }
  }

  const u16* w2p = w2t + (size_t)(wave*16 + l16)*128 + quad*8;
  short8 wb2[4];
  #pragma unroll
  for (int ks=0;ks<4;ks++) wb2[ks] = *(const short8*)(w2p + ks*32);
  __syncthreads();   // layer-1 a-frag reads done before X1 overwrites cols 0..127

  float bias = b1[wave*16 + l16];
  #pragma unroll
  for (int m=0;m<4;m++){
    #pragma unroll
    for (int r=0;r<4;r++){
      int row = m*16 + quad*4 + r;
      float v0 = acc[m][r] + bias; v0 = v0>0.f ? v0 : 0.f;
      xs[row*264 + wave*16 + l16] = f2bf(v0);
    }
  }
  __syncthreads();

  f32x4 acc2[4];
  #pragma unroll
  for (int m=0;m<4;m++) acc2[m]=(f32x4){0,0,0,0};
  #pragma unroll
  for (int ks=0;ks<4;ks++){
    #pragma unroll
    for (int m=0;m<4;m++){
      short8 av = *(const short8*)(&xs[(m*16+l16)*264 + ks*32 + quad*8]);
      acc2[m] = __builtin_amdgcn_mfma_f32_16x16x32_bf16(av, wb2[ks], acc2[m],0,0,0);
    }
  }
  float c0 = b2[wave*16 + l16];
  #pragma unroll
  for (int m=0;m<4;m++){
    #pragma unroll
    for (int r=0;r<4;r++){
      int node = node0 + m*16 + quad*4 + r;
      if (node<n){
        float v0 = acc2[m][r]+c0; v0 = v0>0.f?v0:0.f;
        out[(size_t)node*128 + wave*16 + l16] = v0;
      }
    }
  }
}

extern "C" void kernel_launch(void* const* d_in, const int* in_sizes, int n_in,
                              void* d_out, int out_size, void* d_ws, size_t ws_size,
                              hipStream_t stream){
  const float* h  = (const float*)d_in[0];
  const int*   ei = (const int*)d_in[1];
  const float* W1 = (const float*)d_in[2];
  const float* b1 = (const float*)d_in[3];
  const float* W2 = (const float*)d_in[4];
  const float* b2 = (const float*)d_in[5];
  float* out = (float*)d_out;
  u32* outw  = (u32*)d_out;
  int n  = in_sizes[0] / 128;
  int nE = in_sizes[1] / 2;
  const int* srcI = ei;
  const int* dstI = ei + nE;
  int nbuck = (n + BKT_NODES - 1) >> BKT_SHIFT;   // 782

  // workspace layout — ~20.5 MB
  char* ws = (char*)d_ws;
  u32* recs = (u32*)ws;                               // nbuck*CAP*4 = 4.80 MB
  size_t off = (size_t)nbuck*CAP*4;
  int* gcnt = (int*)(ws + off); off += 4096;          // NBH ints
  u16* hbf  = (u16*)(ws + off); off += (size_t)n*256; // n x 128 bf16 = 12.8 MB
  off = (off + 15) & ~(size_t)15;
  u16* srt_g = (u16*)(ws + off); off += (size_t)nbuck*CAP*2;  // 2.4 MB
  off = (off + 15) & ~(size_t)15;
  u32* nd_g = (u32*)(ws + off); off += (size_t)((n+63)&~63)*4; // 200 KB
  off = (off + 15) & ~(size_t)15;
  u16* w1t  = (u16*)(ws + off);                       // 128x256 bf16
  u16* w2t  = (u16*)(ws + off + 65536);               // 128x128 bf16

  hipMemsetAsync(gcnt, 0, NBH*sizeof(int), stream);
  int gB = (nE + EPB - 1)/EPB;                        // 196 bin blocks (first)
  int nh8 = n*16;
  int castN = nh8 > 49152 ? nh8 : 49152;
  int gC = (castN + 255)/256;
  k_castbin<<<gB+gC, 256, 0, stream>>>(srcI, dstI, gcnt, recs, nE, gB,
                                       h, hbf, nh8, W1, W2, w1t, w2t);
  k_sortscat<<<nbuck, 256, 0, stream>>>(recs, gcnt, srt_g, nd_g, n);
  k_agg<<<(n+3)/4, 256, 0, stream>>>((const u32*)hbf, srt_g, nd_g, outw, n);
  k_mlp<<<nbuck, 512, 0, stream>>>(hbf, outw, w1t, w2t, b1, b2, out, n);
}